// Round 4
// baseline (141.521 us; speedup 1.0000x reference)
//
#include <hip/hip_runtime.h>
#include <math.h>

// ---------------------------------------------------------------------------
// Difflogic network, collapsed form, SINGLE fused kernel.
//   per neuron: out = c0 + c1*p + c2*q + c3*p*q,  p = A·x, q = B·x
//   A,B = softmax(sel), (c0..c3) = softmax(gate_logits) · gate-coef table
//
// Per-block: wave 0 (15 active lanes) computes all 288 derived coefficients
// into LDS (redundantly per block -- ~1us, overlapped with x staging by
// waves 1-3). Body is neuron-major with asm memory fences between neuron
// sections so the scheduler cannot hoist all 288 coefficient loads to the
// entry block (that hoisting is what spilled R2/R3).
//
// scf layout (floats):
//   A1:   0 (72)   B1:  72 (72)   C1: 144 (32)
//   A2: 176 (32)   B2: 208 (32)   C2: 240 (16)
//   A3: 256 ( 8)   B3: 264 ( 8)   C3: 272 ( 8)
//   A4: 280 ( 2)   B4: 282 ( 2)   C4: 284 ( 4)   total 288 floats
// ---------------------------------------------------------------------------

#define THREADS 256
#define SPT 4                          // samples per thread
#define B_PER_BLOCK (THREADS * SPT)    // 1024 samples / block

__global__ __launch_bounds__(THREADS) void fused_net_kernel(
        const float* __restrict__ x,
        const float* __restrict__ sa1, const float* __restrict__ sb1, const float* __restrict__ g1,
        const float* __restrict__ sa2, const float* __restrict__ sb2, const float* __restrict__ g2,
        const float* __restrict__ sa3, const float* __restrict__ sb3, const float* __restrict__ g3,
        const float* __restrict__ sa4, const float* __restrict__ sb4, const float* __restrict__ g4,
        float* __restrict__ out, int nB) {
    __shared__ float scf[288];
    __shared__ float sx[B_PER_BLOCK * 9];          // 36 KB

    const int t = threadIdx.x;
    const int blockBase = blockIdx.x * B_PER_BLOCK;
    const int total = nB * 9;

    if (t < 64) {
        // ---- wave 0: derive coefficients into LDS (15 active lanes) ----
        if (t < 15) {
            const float k0[16]  = {0,0,0,0, 0,0,0,0, 1, 1, 1, 1, 1, 1, 1, 1};
            const float kp[16]  = {0,0,1,1, 0,0,1,1,-1,-1, 0, 0,-1,-1, 0, 0};
            const float kq[16]  = {0,0,0,0, 1,1,1,1,-1,-1,-1,-1, 0, 0, 0, 0};
            const float kpq[16] = {0,1,-1,0,-1,0,-2,-1, 1, 2, 0, 1, 0, 1,-1, 0};

            const float *sa, *sb, *g;
            float *A, *Bc, *C;
            int d;
            if (t < 8)       { int j = t;      d = 9; sa = sa1 + j*9; sb = sb1 + j*9; g = g1 + j*16; A = scf       + j*9; Bc = scf +  72 + j*9; C = scf + 144 + j*4; }
            else if (t < 12) { int j = t - 8;  d = 8; sa = sa2 + j*8; sb = sb2 + j*8; g = g2 + j*16; A = scf + 176 + j*8; Bc = scf + 208 + j*8; C = scf + 240 + j*4; }
            else if (t < 14) { int j = t - 12; d = 4; sa = sa3 + j*4; sb = sb3 + j*4; g = g3 + j*16; A = scf + 256 + j*4; Bc = scf + 264 + j*4; C = scf + 272 + j*4; }
            else             {                 d = 2; sa = sa4;       sb = sb4;       g = g4;        A = scf + 280;       Bc = scf + 282;       C = scf + 284; }

            {   // softmax(sel_a) -> A
                float m = -1e30f;
                for (int i = 0; i < d; ++i) m = fmaxf(m, sa[i]);
                float e[9], s = 0.f;
                for (int i = 0; i < d; ++i) { e[i] = expf(sa[i] - m); s += e[i]; }
                for (int i = 0; i < d; ++i) A[i] = e[i] / s;
            }
            {   // softmax(sel_b) -> B
                float m = -1e30f;
                for (int i = 0; i < d; ++i) m = fmaxf(m, sb[i]);
                float e[9], s = 0.f;
                for (int i = 0; i < d; ++i) { e[i] = expf(sb[i] - m); s += e[i]; }
                for (int i = 0; i < d; ++i) Bc[i] = e[i] / s;
            }
            {   // softmax(gate_logits) folded with gate table -> C[0..3]
                float m = -1e30f;
                for (int i = 0; i < 16; ++i) m = fmaxf(m, g[i]);
                float w[16], s = 0.f;
                for (int i = 0; i < 16; ++i) { w[i] = expf(g[i] - m); s += w[i]; }
                float c0 = 0, c1 = 0, c2 = 0, c3 = 0;
                for (int i = 0; i < 16; ++i) {
                    float wi = w[i] / s;
                    c0 += wi * k0[i]; c1 += wi * kp[i]; c2 += wi * kq[i]; c3 += wi * kpq[i];
                }
                C[0] = c0; C[1] = c1; C[2] = c2; C[3] = c3;
            }
        }
    } else {
        // ---- waves 1-3 (192 threads): stage 2304 float4 = 36 KB of x ----
        const int tt = t - 64;
        const int f4base = blockBase * 9 / 4;      // exact: 2304 float4 / block
        const float4* __restrict__ x4 = (const float4*)x;
        float4* sx4 = (float4*)sx;
        #pragma unroll
        for (int k = 0; k < 12; ++k) {
            int idx = tt + k * 192;                // [0, 2304)
            int fi  = f4base + idx;
            int e   = fi * 4;
            if (e + 3 < total) {
                sx4[idx] = x4[fi];
            } else {
                float4 vv = {0.f, 0.f, 0.f, 0.f};
                if (e     < total) vv.x = x[e];
                if (e + 1 < total) vv.y = x[e + 1];
                if (e + 2 < total) vv.z = x[e + 2];
                sx4[idx] = vv;
            }
        }
    }
    __syncthreads();

    // Pull this thread's 4 samples into registers. Row stride 9 words (odd)
    // -> 2 lanes/bank max alias, free on gfx950.
    float v[SPT][9];
    #pragma unroll
    for (int s = 0; s < SPT; ++s) {
        const int r = s * THREADS + t;
        #pragma unroll
        for (int i = 0; i < 9; ++i) v[s][i] = sx[r * 9 + i];
    }
    asm volatile("" ::: "memory");

    // ---- Layer 1: 9 -> 8, neuron-major; fence pins each section's loads ----
    float h1[SPT][8];
    #pragma unroll
    for (int j = 0; j < 8; ++j) {
        float A[9], Bv[9], C4[4];
        #pragma unroll
        for (int i = 0; i < 9; ++i) { A[i] = scf[j * 9 + i]; Bv[i] = scf[72 + j * 9 + i]; }
        #pragma unroll
        for (int c = 0; c < 4; ++c) C4[c] = scf[144 + j * 4 + c];
        #pragma unroll
        for (int s = 0; s < SPT; ++s) {
            float p = 0.f, q = 0.f;
            #pragma unroll
            for (int i = 0; i < 9; ++i) { p = fmaf(v[s][i], A[i], p); q = fmaf(v[s][i], Bv[i], q); }
            h1[s][j] = fmaf(C4[3], p * q, fmaf(C4[2], q, fmaf(C4[1], p, C4[0])));
        }
        asm volatile("" ::: "memory");
    }
    // ---- Layer 2: 8 -> 4 ----
    float h2[SPT][4];
    #pragma unroll
    for (int j = 0; j < 4; ++j) {
        float A[8], Bv[8], C4[4];
        #pragma unroll
        for (int i = 0; i < 8; ++i) { A[i] = scf[176 + j * 8 + i]; Bv[i] = scf[208 + j * 8 + i]; }
        #pragma unroll
        for (int c = 0; c < 4; ++c) C4[c] = scf[240 + j * 4 + c];
        #pragma unroll
        for (int s = 0; s < SPT; ++s) {
            float p = 0.f, q = 0.f;
            #pragma unroll
            for (int i = 0; i < 8; ++i) { p = fmaf(h1[s][i], A[i], p); q = fmaf(h1[s][i], Bv[i], q); }
            h2[s][j] = fmaf(C4[3], p * q, fmaf(C4[2], q, fmaf(C4[1], p, C4[0])));
        }
        asm volatile("" ::: "memory");
    }
    // ---- Layer 3: 4 -> 2 ----
    float h3[SPT][2];
    #pragma unroll
    for (int j = 0; j < 2; ++j) {
        float A[4], Bv[4], C4[4];
        #pragma unroll
        for (int i = 0; i < 4; ++i) { A[i] = scf[256 + j * 4 + i]; Bv[i] = scf[264 + j * 4 + i]; }
        #pragma unroll
        for (int c = 0; c < 4; ++c) C4[c] = scf[272 + j * 4 + c];
        #pragma unroll
        for (int s = 0; s < SPT; ++s) {
            float p = 0.f, q = 0.f;
            #pragma unroll
            for (int i = 0; i < 4; ++i) { p = fmaf(h2[s][i], A[i], p); q = fmaf(h2[s][i], Bv[i], q); }
            h3[s][j] = fmaf(C4[3], p * q, fmaf(C4[2], q, fmaf(C4[1], p, C4[0])));
        }
        asm volatile("" ::: "memory");
    }
    // ---- Layer 4: 2 -> 1, coalesced dword stores ----
    {
        float a0 = scf[280], a1 = scf[281], b0 = scf[282], b1 = scf[283];
        float c0 = scf[284], c1 = scf[285], c2 = scf[286], c3 = scf[287];
        #pragma unroll
        for (int s = 0; s < SPT; ++s) {
            float p = fmaf(h3[s][0], a0, h3[s][1] * a1);
            float q = fmaf(h3[s][0], b0, h3[s][1] * b1);
            float o = fmaf(c3, p * q, fmaf(c2, q, fmaf(c1, p, c0)));
            int b = blockBase + s * THREADS + t;
            if (b < nB) out[b] = o;
        }
    }
}

extern "C" void kernel_launch(void* const* d_in, const int* in_sizes, int n_in,
                              void* d_out, int out_size, void* d_ws, size_t ws_size,
                              hipStream_t stream) {
    const float* x   = (const float*)d_in[0];
    const float* sa1 = (const float*)d_in[1];
    const float* sb1 = (const float*)d_in[2];
    const float* g1  = (const float*)d_in[3];
    const float* sa2 = (const float*)d_in[4];
    const float* sb2 = (const float*)d_in[5];
    const float* g2  = (const float*)d_in[6];
    const float* sa3 = (const float*)d_in[7];
    const float* sb3 = (const float*)d_in[8];
    const float* g3  = (const float*)d_in[9];
    const float* sa4 = (const float*)d_in[10];
    const float* sb4 = (const float*)d_in[11];
    const float* g4  = (const float*)d_in[12];
    const int nB = in_sizes[0] / 9;

    const int grid = (nB + B_PER_BLOCK - 1) / B_PER_BLOCK;
    fused_net_kernel<<<grid, THREADS, 0, stream>>>(
        x, sa1, sb1, g1, sa2, sb2, g2, sa3, sb3, g3, sa4, sb4, g4,
        (float*)d_out, nB);
}

// Round 5
// 107.601 us; speedup vs baseline: 1.3152x; 1.3152x over previous
//
#include <hip/hip_runtime.h>
#include <math.h>

// ---------------------------------------------------------------------------
// Difflogic network, collapsed form:
//   per neuron: out = c0 + c1*p + c2*q + c3*p*q,  p = A·x, q = B·x
//   A,B = softmax(sel), (c0..c3) = softmax(gate_logits) · gate-coef table
//
// R4 -> R5: removed ALL shared memory, barriers, fences, and the per-block
// redundant coefficient derivation (R4: 60us, VALUBusy 19%, occ 10% --
// latency-bound on a barriered LDS structure). Now: tiny coeff kernel -> ws,
// main kernel loads x as 9 contiguous dwordx4 per thread (4 samples/thread,
// no cross-thread reuse exists), coefficients via constant-offset uniform
// loads (s_load, SGPR operands straight into v_fma), float4 stores.
//
// ws layout (floats):
//   A1:   0 (72)   B1:  72 (72)   C1: 144 (32)
//   A2: 176 (32)   B2: 208 (32)   C2: 240 (16)
//   A3: 256 ( 8)   B3: 264 ( 8)   C3: 272 ( 8)
//   A4: 280 ( 2)   B4: 282 ( 2)   C4: 284 ( 4)   total 288 floats = 1152 B
// ---------------------------------------------------------------------------

#define THREADS 256
#define SPT 4                          // consecutive samples per thread
#define B_PER_BLOCK (THREADS * SPT)

template <int D>
__device__ __forceinline__ void softmax_row(const float* __restrict__ src,
                                            float* __restrict__ dst) {
    float e[D];
    float m = src[0];
    #pragma unroll
    for (int i = 1; i < D; ++i) m = fmaxf(m, src[i]);
    float s = 0.f;
    #pragma unroll
    for (int i = 0; i < D; ++i) { e[i] = __expf(src[i] - m); s += e[i]; }
    float inv = 1.f / s;
    #pragma unroll
    for (int i = 0; i < D; ++i) dst[i] = e[i] * inv;
}

__device__ __forceinline__ void gate_fold(const float* __restrict__ g,
                                          float* __restrict__ C) {
    const float k0[16]  = {0,0,0,0, 0,0,0,0, 1, 1, 1, 1, 1, 1, 1, 1};
    const float kp[16]  = {0,0,1,1, 0,0,1,1,-1,-1, 0, 0,-1,-1, 0, 0};
    const float kq[16]  = {0,0,0,0, 1,1,1,1,-1,-1,-1,-1, 0, 0, 0, 0};
    const float kpq[16] = {0,1,-1,0,-1,0,-2,-1, 1, 2, 0, 1, 0, 1,-1, 0};
    float w[16];
    float m = g[0];
    #pragma unroll
    for (int i = 1; i < 16; ++i) m = fmaxf(m, g[i]);
    float s = 0.f;
    #pragma unroll
    for (int i = 0; i < 16; ++i) { w[i] = __expf(g[i] - m); s += w[i]; }
    float inv = 1.f / s;
    float c0 = 0, c1 = 0, c2 = 0, c3 = 0;
    #pragma unroll
    for (int i = 0; i < 16; ++i) {
        float wi = w[i] * inv;
        c0 = fmaf(wi, k0[i], c0); c1 = fmaf(wi, kp[i], c1);
        c2 = fmaf(wi, kq[i], c2); c3 = fmaf(wi, kpq[i], c3);
    }
    C[0] = c0; C[1] = c1; C[2] = c2; C[3] = c3;
}

__global__ void coeff_kernel(const float* __restrict__ sa1, const float* __restrict__ sb1, const float* __restrict__ g1,
                             const float* __restrict__ sa2, const float* __restrict__ sb2, const float* __restrict__ g2,
                             const float* __restrict__ sa3, const float* __restrict__ sb3, const float* __restrict__ g3,
                             const float* __restrict__ sa4, const float* __restrict__ sb4, const float* __restrict__ g4,
                             float* __restrict__ cf) {
    int t = threadIdx.x;
    if (t < 8) {            // layer 1 rows, d=9 (compile-time -> batched loads)
        int j = t;
        softmax_row<9>(sa1 + j * 9, cf + j * 9);
        softmax_row<9>(sb1 + j * 9, cf + 72 + j * 9);
        gate_fold(g1 + j * 16, cf + 144 + j * 4);
    } else if (t < 12) {    // layer 2, d=8
        int j = t - 8;
        softmax_row<8>(sa2 + j * 8, cf + 176 + j * 8);
        softmax_row<8>(sb2 + j * 8, cf + 208 + j * 8);
        gate_fold(g2 + j * 16, cf + 240 + j * 4);
    } else if (t < 14) {    // layer 3, d=4
        int j = t - 12;
        softmax_row<4>(sa3 + j * 4, cf + 256 + j * 4);
        softmax_row<4>(sb3 + j * 4, cf + 264 + j * 4);
        gate_fold(g3 + j * 16, cf + 272 + j * 4);
    } else if (t == 14) {   // layer 4, d=2
        softmax_row<2>(sa4, cf + 280);
        softmax_row<2>(sb4, cf + 282);
        gate_fold(g4, cf + 284);
    }
}

__global__ __launch_bounds__(THREADS, 3) void net_kernel(
        const float* __restrict__ x, const float* __restrict__ cf,
        float* __restrict__ out, int nB) {
    const int T  = blockIdx.x * THREADS + threadIdx.x;  // sample-group id
    const int b0 = T * SPT;
    if (b0 >= nB) return;

    // ---- load 4 consecutive samples = 36 contiguous floats = 9 dwordx4 ----
    float v[SPT][9];
    if (b0 + SPT <= nB) {
        const float4* __restrict__ x4 = (const float4*)x;
        float4 r[9];
        #pragma unroll
        for (int k = 0; k < 9; ++k) r[k] = x4[(long)T * 9 + k];
        const float* rf = (const float*)r;   // constant-index after unroll -> stays in VGPRs
        #pragma unroll
        for (int s = 0; s < SPT; ++s)
            #pragma unroll
            for (int i = 0; i < 9; ++i) v[s][i] = rf[s * 9 + i];
    } else {
        #pragma unroll
        for (int s = 0; s < SPT; ++s)
            #pragma unroll
            for (int i = 0; i < 9; ++i) {
                int b = b0 + s;
                v[s][i] = (b < nB) ? x[(long)b * 9 + i] : 0.f;
            }
    }

    // ---- Layer 1: 9 -> 8. cf[] uses are uniform-pointer + constant offset
    //      -> scalar loads; SGPR operands feed v_fma directly. ----
    float h1[SPT][8];
    #pragma unroll
    for (int j = 0; j < 8; ++j) {
        #pragma unroll
        for (int s = 0; s < SPT; ++s) {
            float p = 0.f, q = 0.f;
            #pragma unroll
            for (int i = 0; i < 9; ++i) {
                p = fmaf(v[s][i], cf[     j * 9 + i], p);
                q = fmaf(v[s][i], cf[72 + j * 9 + i], q);
            }
            h1[s][j] = fmaf(cf[144 + j*4 + 3], p * q,
                       fmaf(cf[144 + j*4 + 2], q,
                       fmaf(cf[144 + j*4 + 1], p, cf[144 + j*4 + 0])));
        }
    }
    // ---- Layer 2: 8 -> 4 ----
    float h2[SPT][4];
    #pragma unroll
    for (int j = 0; j < 4; ++j) {
        #pragma unroll
        for (int s = 0; s < SPT; ++s) {
            float p = 0.f, q = 0.f;
            #pragma unroll
            for (int i = 0; i < 8; ++i) {
                p = fmaf(h1[s][i], cf[176 + j * 8 + i], p);
                q = fmaf(h1[s][i], cf[208 + j * 8 + i], q);
            }
            h2[s][j] = fmaf(cf[240 + j*4 + 3], p * q,
                       fmaf(cf[240 + j*4 + 2], q,
                       fmaf(cf[240 + j*4 + 1], p, cf[240 + j*4 + 0])));
        }
    }
    // ---- Layer 3: 4 -> 2 ----
    float h3[SPT][2];
    #pragma unroll
    for (int j = 0; j < 2; ++j) {
        #pragma unroll
        for (int s = 0; s < SPT; ++s) {
            float p = 0.f, q = 0.f;
            #pragma unroll
            for (int i = 0; i < 4; ++i) {
                p = fmaf(h2[s][i], cf[256 + j * 4 + i], p);
                q = fmaf(h2[s][i], cf[264 + j * 4 + i], q);
            }
            h3[s][j] = fmaf(cf[272 + j*4 + 3], p * q,
                       fmaf(cf[272 + j*4 + 2], q,
                       fmaf(cf[272 + j*4 + 1], p, cf[272 + j*4 + 0])));
        }
    }
    // ---- Layer 4: 2 -> 1, one float4 store per thread ----
    float o[SPT];
    #pragma unroll
    for (int s = 0; s < SPT; ++s) {
        float p = fmaf(h3[s][0], cf[280], h3[s][1] * cf[281]);
        float q = fmaf(h3[s][0], cf[282], h3[s][1] * cf[283]);
        o[s] = fmaf(cf[287], p * q,
               fmaf(cf[286], q,
               fmaf(cf[285], p, cf[284])));
    }
    if (b0 + SPT <= nB) {
        float4* __restrict__ out4 = (float4*)out;
        float4 w; w.x = o[0]; w.y = o[1]; w.z = o[2]; w.w = o[3];
        out4[T] = w;
    } else {
        #pragma unroll
        for (int s = 0; s < SPT; ++s)
            if (b0 + s < nB) out[b0 + s] = o[s];
    }
}

extern "C" void kernel_launch(void* const* d_in, const int* in_sizes, int n_in,
                              void* d_out, int out_size, void* d_ws, size_t ws_size,
                              hipStream_t stream) {
    const float* x   = (const float*)d_in[0];
    const float* sa1 = (const float*)d_in[1];
    const float* sb1 = (const float*)d_in[2];
    const float* g1  = (const float*)d_in[3];
    const float* sa2 = (const float*)d_in[4];
    const float* sb2 = (const float*)d_in[5];
    const float* g2  = (const float*)d_in[6];
    const float* sa3 = (const float*)d_in[7];
    const float* sb3 = (const float*)d_in[8];
    const float* g3  = (const float*)d_in[9];
    const float* sa4 = (const float*)d_in[10];
    const float* sb4 = (const float*)d_in[11];
    const float* g4  = (const float*)d_in[12];
    float* cf = (float*)d_ws;                 // 288 floats of scratch
    const int nB = in_sizes[0] / 9;

    coeff_kernel<<<1, 64, 0, stream>>>(sa1, sb1, g1, sa2, sb2, g2,
                                       sa3, sb3, g3, sa4, sb4, g4, cf);
    const int grid = (nB + B_PER_BLOCK - 1) / B_PER_BLOCK;
    net_kernel<<<grid, THREADS, 0, stream>>>(x, cf, (float*)d_out, nB);
}